// Round 21
// baseline (437.503 us; speedup 1.0000x reference)
//
#include <hip/hip_runtime.h>

#define NPTS 2048
#define BATCH 8
#define KNN 20
#define KSPLIT 4

typedef short short8v __attribute__((ext_vector_type(8)));
typedef float f32x4 __attribute__((ext_vector_type(4)));

__device__ __forceinline__ float leaky(float y) { return fmaxf(y, 0.2f * y); }

__device__ __forceinline__ short f2bf(float f) {
  unsigned u = __float_as_uint(f);
  unsigned r = (u + 0x7fffu + ((u >> 16) & 1u)) >> 16;
  return (short)r;
}
__device__ __forceinline__ float bf2f(short h) {
  return __uint_as_float(((unsigned)(unsigned short)h) << 16);
}

// med3(key, lo, hi) == min(max(key, lo), hi) when lo <= hi (sorted-list insert step).
__device__ __forceinline__ unsigned med3u(unsigned key, unsigned lo, unsigned hi) {
  unsigned t;
  asm("v_med3_u32 %0, %1, %2, %3" : "=v"(t) : "v"(key), "v"(lo), "v"(hi));
  return t;
}

// ---------------- prep edge-conv weight -> hi/lo bf16 quads, fragment layout ----------------
__global__ void prep_wpq_kernel(const float* __restrict__ W, const float* __restrict__ g,
                                short* __restrict__ wph, short* __restrict__ wpl,
                                int O, int C, int P2, int NCHUNK) {
  int t = blockIdx.x * 256 + threadIdx.x;
  if (t >= NCHUNK * 4 * P2) return;
  int cg = t / P2, p = t - cg * P2;
  int chunk = cg >> 2, gg = cg & 3;
  int po = (p < O) ? p : p - O;
  float s = g[po] * rsqrtf(1.0f + 1e-5f);
  short8v h8, l8;
  #pragma unroll
  for (int j = 0; j < 8; ++j) {
    int c = chunk * 32 + gg * 4 + (j & 3) + 16 * (j >> 2);
    float v = 0.f;
    if (c < C) {
      v = (p < O) ? s * W[p * 2 * C + c]
                  : s * (W[po * 2 * C + C + c] - W[po * 2 * C + c]);
    }
    short h = f2bf(v);
    h8[j] = h;
    l8[j] = f2bf(v - bf2f(h));
  }
  *reinterpret_cast<short8v*>(wph + (long)t * 8) = h8;
  *reinterpret_cast<short8v*>(wpl + (long)t * 8) = l8;
}

// prep mlp weight -> hi/lo bf16 quads, fragment layout, bn scale folded
__global__ void prep_wq_kernel(const float* __restrict__ W, const float* __restrict__ g,
                               short* __restrict__ wqh, short* __restrict__ wql) {
  int t = blockIdx.x * 256 + threadIdx.x;   // cg*1024 + o, cg < 64
  if (t >= 64 * 1024) return;
  int cg = t >> 10, o = t & 1023;
  int chunk = cg >> 2, gg = cg & 3;
  float scale = g[o] * rsqrtf(1.0f + 1e-5f);
  short8v h8, l8;
  #pragma unroll
  for (int j = 0; j < 8; ++j) {
    int c = chunk * 32 + gg * 4 + (j & 3) + 16 * (j >> 2);
    float v = scale * W[o * 512 + c];
    short h = f2bf(v);
    h8[j] = h;
    l8[j] = f2bf(v - bf2f(h));
  }
  *reinterpret_cast<short8v*>(wqh + (long)t * 8) = h8;
  *reinterpret_cast<short8v*>(wql + (long)t * 8) = l8;
}

// ---------------- xx[b][m] = sum_c x[c][m]^2 (exact fp32) ----------------
__global__ void xx_kernel(const float* __restrict__ x, float* __restrict__ xx,
                          int C, long bstride) {
  int b = blockIdx.y;
  int m = blockIdx.x * 256 + threadIdx.x;
  const float* xb = x + (long)b * bstride;
  float s = 0.f;
  for (int c = 0; c < C; ++c) { float v = xb[c * NPTS + m]; s += v * v; }
  xx[b * NPTS + m] = s;
}

// ---------------- split x into hi/lo bf16 fragment layout ----------------
__global__ void split_kernel(const float* __restrict__ x, short* __restrict__ xfh,
                             short* __restrict__ xfl, int C, int NCHUNK, long bstride) {
  int b = blockIdx.y;
  int t = blockIdx.x * 256 + threadIdx.x;   // cg*2048 + n
  int cg = t >> 11, n = t & 2047;
  int chunk = cg >> 2, g = cg & 3;
  const float* xb = x + (long)b * bstride;
  short8v h8, l8;
  #pragma unroll
  for (int j = 0; j < 8; ++j) {
    int c = chunk * 32 + g * 4 + (j & 3) + 16 * (j >> 2);
    float v = (c < C) ? xb[c * NPTS + n] : 0.f;
    short h = f2bf(v);
    float lo = v - bf2f(h);
    h8[j] = h;
    l8[j] = f2bf(lo);
  }
  long q = (long)b * NCHUNK * 4 * 2048 + t;
  *reinterpret_cast<short8v*>(xfh + q * 8) = h8;
  *reinterpret_cast<short8v*>(xfl + q * 8) = l8;
}

// ---------------- split xcat (all 512 ch) for mlp ----------------
__global__ void mlp_split_kernel(const float* __restrict__ xcat, short* __restrict__ xqh,
                                 short* __restrict__ xql) {
  int b = blockIdx.y;
  int t = blockIdx.x * 256 + threadIdx.x;   // cg*2048 + n, cg < 64
  int cg = t >> 11, n = t & 2047;
  int chunk = cg >> 2, g = cg & 3;
  const float* xb = xcat + (long)b * 512 * NPTS;
  short8v h8, l8;
  #pragma unroll
  for (int j = 0; j < 8; ++j) {
    int c = chunk * 32 + g * 4 + (j & 3) + 16 * (j >> 2);
    float v = xb[c * NPTS + n];
    short h = f2bf(v);
    h8[j] = h;
    l8[j] = f2bf(v - bf2f(h));
  }
  long q = (long)b * 64 * 2048 + t;
  *reinterpret_cast<short8v*>(xqh + q * 8) = h8;
  *reinterpret_cast<short8v*>(xql + q * 8) = l8;
}

// ---------------- knn scan: swapped-operand MFMA (3-product) + packed-u32 top-20 ----------------
template <int NCHUNK>
__global__ __launch_bounds__(256, 4) void knn_scan(const short* __restrict__ xfh,
                                                   const short* __restrict__ xfl,
                                                   const float* __restrict__ xx,
                                                   unsigned* __restrict__ pd) {
  __shared__ __align__(16) float smem[2080];   // qsm: 520 quads (8320 B)
  short8v* qsm = (short8v*)smem;
  unsigned* mD = (unsigned*)smem;              // alias (epilogue): [64][20] u32

  int tid = threadIdx.x;
  int lane = tid & 63, wv = tid >> 6;
  int pt = lane & 15;
  int kg = lane >> 4;
  int b = blockIdx.z;
  int sidx = blockIdx.y;
  int n0 = blockIdx.x * 64;
  const float* xxb = xx + b * NPTS;
  const short8v* xfh_b = (const short8v*)xfh + (long)b * NCHUNK * 4 * 2048;
  const short8v* xfl_b = (const short8v*)xfl + (long)b * NCHUNK * 4 * 2048;

  short8v bfh[NCHUNK], bfl[NCHUNK];
  #pragma unroll
  for (int c = 0; c < NCHUNK; ++c) {
    long qi = ((long)(c * 4 + kg)) * 2048 + n0 + wv * 16 + pt;
    bfh[c] = xfh_b[qi];
    bfl[c] = xfl_b[qi];
  }
  float xn = xxb[n0 + wv * 16 + pt];

  unsigned pl[20];
  #pragma unroll
  for (int k = 0; k < 20; ++k) pl[k] = 0xFFFFFFFFu;

  int mt0 = sidx * (32 / KSPLIT);

  short8v pA, pB;
  {
    long qi = ((long)(0 * 4 + wv)) * 2048 + mt0 * 64 + lane;
    pA = xfh_b[qi];
    pB = xfl_b[qi];
  }

  for (int mtl = 0; mtl < 32 / KSPLIT; ++mtl) {
    int m0 = (mt0 + mtl) * 64;
    float xpm[4][4];
    #pragma unroll
    for (int f = 0; f < 4; ++f) {
      f32x4 q = *reinterpret_cast<const f32x4*>(&xxb[m0 + f * 16 + kg * 4]);
      #pragma unroll
      for (int r = 0; r < 4; ++r) xpm[f][r] = (xn + 4.0f) + q[r];
    }
    f32x4 acc[4];
    #pragma unroll
    for (int f = 0; f < 4; ++f) acc[f] = (f32x4){0.f, 0.f, 0.f, 0.f};

    #pragma unroll
    for (int c = 0; c < NCHUNK; ++c) {
      __syncthreads();
      qsm[wv * 65 + lane] = pA;
      qsm[(4 + wv) * 65 + lane] = pB;
      __syncthreads();
      int nm = mtl, nc = c + 1;
      if (nc == NCHUNK) { nc = 0; nm = mtl + 1; }
      if (nm < 32 / KSPLIT) {
        long qi = ((long)(nc * 4 + wv)) * 2048 + (mt0 + nm) * 64 + lane;
        pA = xfh_b[qi];
        pB = xfl_b[qi];
      }
      // 3 products: hh, h*l, l*h (ll term ~2^-18 rel, far below key truncation)
      __builtin_amdgcn_s_setprio(1);
      #pragma unroll
      for (int f = 0; f < 4; ++f) {
        short8v ah = qsm[kg * 65 + f * 16 + pt];
        short8v al = qsm[(4 + kg) * 65 + f * 16 + pt];
        acc[f] = __builtin_amdgcn_mfma_f32_16x16x32_bf16(ah, bfh[c], acc[f], 0, 0, 0);
        acc[f] = __builtin_amdgcn_mfma_f32_16x16x32_bf16(ah, bfl[c], acc[f], 0, 0, 0);
        acc[f] = __builtin_amdgcn_mfma_f32_16x16x32_bf16(al, bfh[c], acc[f], 0, 0, 0);
      }
      __builtin_amdgcn_s_setprio(0);
    }

    #pragma unroll
    for (int f = 0; f < 4; ++f) {
      #pragma unroll
      for (int r = 0; r < 4; ++r) {
        float v = fmaf(-2.f, acc[f][r], xpm[f][r]);   // d2 + 4.0 (biased, positive)
        unsigned key = (__float_as_uint(v) & 0xFFFFF800u) | (unsigned)(m0 + f * 16 + kg * 4 + r);
        #pragma unroll
        for (int k = 19; k >= 1; --k)
          pl[k] = med3u(key, pl[k - 1], pl[k]);
        pl[0] = min(key, pl[0]);
      }
    }
  }
  __syncthreads();   // all MFMA/qsm use done; safe to alias mD

  // in-wave 4-way merge: point n's lists live at lanes {pt, pt+16, pt+32, pt+48}
  unsigned h = pl[0];
  #pragma unroll
  for (int k = 0; k < KNN; ++k) {
    unsigned v0 = (unsigned)__shfl((int)h, pt);
    unsigned v1 = (unsigned)__shfl((int)h, pt + 16);
    unsigned v2 = (unsigned)__shfl((int)h, pt + 32);
    unsigned v3 = (unsigned)__shfl((int)h, pt + 48);
    unsigned bv = v0; int bp = 0;
    if (v1 < bv) { bv = v1; bp = 1; }
    if (v2 < bv) { bv = v2; bp = 2; }
    if (v3 < bv) { bv = v3; bp = 3; }
    if (kg == 0) mD[(wv * 16 + pt) * KNN + k] = bv;
    bool pop = (kg == bp);
    #pragma unroll
    for (int i = 0; i < 19; ++i) pl[i] = pop ? pl[i + 1] : pl[i];
    pl[19] = pop ? 0xFFFFFFFFu : pl[19];
    h = pl[0];
  }
  __syncthreads();

  long base = ((long)((b * KSPLIT + sidx) * NPTS) + n0) * KNN;
  #pragma unroll
  for (int s = 0; s < 5; ++s) pd[base + s * 256 + tid] = mD[s * 256 + tid];
}

// ---------------- vsus via MFMA hi/lo (3 products): out[b][n][p] ----------------
template <int NCHUNK>
__global__ __launch_bounds__(256) void vsus_mfma_kernel(const short* __restrict__ xfh,
                                                        const short* __restrict__ xfl,
                                                        const short* __restrict__ wph,
                                                        const short* __restrict__ wpl,
                                                        float* __restrict__ out, int P2) {
  __shared__ __align__(16) short8v qsmX[2 * 4 * 130];   // [hl][g][130] quads
  int tid = threadIdx.x;
  int lane = tid & 63, wv = tid >> 6;
  int pt = lane & 15, kg = lane >> 4;
  int b = blockIdx.z, pb = blockIdx.y, nt = blockIdx.x;
  int n0 = nt * 128;
  int pw = pb * 128 + (wv >> 1) * 64;
  int nwoff = (wv & 1) * 64;
  const short8v* xh_b = (const short8v*)xfh + (long)b * NCHUNK * 4 * 2048;
  const short8v* xl_b = (const short8v*)xfl + (long)b * NCHUNK * 4 * 2048;
  const short8v* wh_q = (const short8v*)wph;
  const short8v* wl_q = (const short8v*)wpl;

  f32x4 acc[4][4];
  #pragma unroll
  for (int f2 = 0; f2 < 4; ++f2)
    #pragma unroll
    for (int fb = 0; fb < 4; ++fb) acc[f2][fb] = (f32x4){0.f, 0.f, 0.f, 0.f};

  for (int chunk = 0; chunk < NCHUNK; ++chunk) {
    __syncthreads();
    #pragma unroll
    for (int s = 0; s < 4; ++s) {
      int idx = s * 256 + tid;        // 0..1023
      int hl = idx >> 9, rem = idx & 511, g = rem >> 7, n = rem & 127;
      const short8v* src = hl ? xl_b : xh_b;
      qsmX[hl * 520 + g * 130 + n] = src[(long)(chunk * 4 + g) * 2048 + n0 + n];
    }
    __syncthreads();
    short8v ah[4], al[4];
    #pragma unroll
    for (int f2 = 0; f2 < 4; ++f2) {
      long qi = (long)(chunk * 4 + kg) * P2 + pw + f2 * 16 + pt;
      ah[f2] = wh_q[qi];
      al[f2] = wl_q[qi];
    }
    __builtin_amdgcn_s_setprio(1);
    #pragma unroll
    for (int fb = 0; fb < 4; ++fb) {
      short8v bh = qsmX[0 * 520 + kg * 130 + nwoff + fb * 16 + pt];
      short8v bl = qsmX[1 * 520 + kg * 130 + nwoff + fb * 16 + pt];
      #pragma unroll
      for (int f2 = 0; f2 < 4; ++f2) {
        acc[f2][fb] = __builtin_amdgcn_mfma_f32_16x16x32_bf16(ah[f2], bh, acc[f2][fb], 0, 0, 0);
        acc[f2][fb] = __builtin_amdgcn_mfma_f32_16x16x32_bf16(al[f2], bh, acc[f2][fb], 0, 0, 0);
        acc[f2][fb] = __builtin_amdgcn_mfma_f32_16x16x32_bf16(ah[f2], bl, acc[f2][fb], 0, 0, 0);
      }
    }
    __builtin_amdgcn_s_setprio(0);
  }

  #pragma unroll
  for (int f2 = 0; f2 < 4; ++f2) {
    #pragma unroll
    for (int fb = 0; fb < 4; ++fb) {
      int n = n0 + nwoff + fb * 16 + pt;
      *reinterpret_cast<f32x4*>(out + (long)(b * NPTS + n) * P2 + pw + f2 * 16 + kg * 4) =
          acc[f2][fb];
    }
  }
}

// ---------------- fused merge + gather + max_k + leaky -> xcat channel block ----------------
// 1D grid, b = blockIdx.x & 7 (XCD-affine): per-XCD vsus working set ~4.2 MB ~= L2.
__global__ __launch_bounds__(256) void gather_max_kernel(const float* __restrict__ vsus,
                                                         const unsigned* __restrict__ pd,
                                                         const float* __restrict__ bias,
                                                         float* __restrict__ xcat,
                                                         int O, int cho) {
  __shared__ __align__(16) float smemA[640 + 256 * 33];
  int* idxs = (int*)smemA;                       // [32][20]
  unsigned* plists = (unsigned*)(smemA + 640);   // phase 1: [4][32][20] u32 (10 KB)
  float* ot = smemA + 640;                       // phase 2: [256][33]

  int tid = threadIdx.x;
  int lin = blockIdx.x;
  int b = lin & 7;
  int n0 = (lin >> 3) * 32;
  int P2 = 2 * O;

  // phase 1: stage partial lists (each s-segment is contiguous in pd)
  for (int i = tid; i < KSPLIT * 32 * KNN; i += 256) {
    int s = i / (32 * KNN), rem = i - s * (32 * KNN);
    plists[i] = pd[((long)((b * KSPLIT + s) * NPTS) + n0) * KNN + rem];
  }
  __syncthreads();
  if (tid < 32) {
    int h0 = 0, h1 = 0, h2 = 0, h3 = 0;
    int base = tid * KNN;
    for (int k = 0; k < KNN; ++k) {
      unsigned v0 = plists[0 * 640 + base + h0];
      unsigned v1 = plists[1 * 640 + base + h1];
      unsigned v2 = plists[2 * 640 + base + h2];
      unsigned v3 = plists[3 * 640 + base + h3];
      unsigned bv = v0; int bp = 0;
      if (v1 < bv) { bv = v1; bp = 1; }
      if (v2 < bv) { bv = v2; bp = 2; }
      if (v3 < bv) { bv = v3; bp = 3; }
      idxs[base + k] = (int)(bv & 0x7FFu);
      h0 += (bp == 0); h1 += (bp == 1); h2 += (bp == 2); h3 += (bp == 3);
    }
  }
  __syncthreads();

  // phase 2: gather-max (plists dead; ot takes over the region)
  int G = 256 / O;
  int o = tid % O;
  int ns = tid / O;
  float bo = bias[o];
  const float* vb = vsus + (long)b * NPTS * P2;
  for (int step = 0; step < 32 / G; ++step) {
    int nn = step * G + ns;
    float mx = -1e30f;
    for (int k = 0; k < KNN; ++k) {
      int j = idxs[nn * KNN + k];
      mx = fmaxf(mx, vb[j * P2 + o]);
    }
    float us = vb[(n0 + nn) * P2 + O + o] + bo;
    ot[o * 33 + nn] = leaky(mx + us);
  }
  __syncthreads();
  float* ob = xcat + ((long)b * 512 + cho) * NPTS + n0;
  for (int i = tid; i < O * 32; i += 256) {
    int oo = i >> 5, nn = i & 31;
    ob[oo * NPTS + nn] = ot[oo * 33 + nn];
  }
}

// ---------------- mlp: MFMA hi/lo (3 products), 128x128 block, fused max/sum ----------------
__global__ __launch_bounds__(256) void mlp_kernel(const short* __restrict__ xqh,
                                                  const short* __restrict__ xql,
                                                  const short* __restrict__ wqh,
                                                  const short* __restrict__ wql,
                                                  const float* __restrict__ bvec,
                                                  float* __restrict__ pbuf) {
  __shared__ __align__(16) short8v qsmX[2 * 4 * 130];   // [hl][g][130] quads
  __shared__ float redM[4][64];
  __shared__ float redS[4][64];
  int tid = threadIdx.x;
  int lane = tid & 63, wv = tid >> 6;
  int pt = lane & 15, kg = lane >> 4;
  int b = blockIdx.z, ob = blockIdx.y, nt = blockIdx.x;
  int o0 = ob * 128, n0 = nt * 128;
  int ow = o0 + (wv >> 1) * 64;
  int nwoff = (wv & 1) * 64;
  const short8v* xqh_b = (const short8v*)xqh + (long)b * 64 * 2048;
  const short8v* xql_b = (const short8v*)xql + (long)b * 64 * 2048;
  const short8v* wqh_q = (const short8v*)wqh;
  const short8v* wql_q = (const short8v*)wql;

  f32x4 acc[4][4];
  #pragma unroll
  for (int f2 = 0; f2 < 4; ++f2)
    #pragma unroll
    for (int fb = 0; fb < 4; ++fb) acc[f2][fb] = (f32x4){0.f, 0.f, 0.f, 0.f};

  for (int chunk = 0; chunk < 16; ++chunk) {
    __syncthreads();
    #pragma unroll
    for (int s = 0; s < 4; ++s) {
      int idx = s * 256 + tid;        // 0..1023
      int hl = idx >> 9, rem = idx & 511, g = rem >> 7, n = rem & 127;
      const short8v* src = hl ? xql_b : xqh_b;
      qsmX[hl * 520 + g * 130 + n] = src[(long)(chunk * 4 + g) * 2048 + n0 + n];
    }
    __syncthreads();
    short8v ah[4], al[4];
    #pragma unroll
    for (int f2 = 0; f2 < 4; ++f2) {
      long qi = (long)(chunk * 4 + kg) * 1024 + ow + f2 * 16 + pt;
      ah[f2] = wqh_q[qi];
      al[f2] = wql_q[qi];
    }
    __builtin_amdgcn_s_setprio(1);
    #pragma unroll
    for (int fb = 0; fb < 4; ++fb) {
      short8v bh = qsmX[0 * 520 + kg * 130 + nwoff + fb * 16 + pt];
      short8v bl = qsmX[1 * 520 + kg * 130 + nwoff + fb * 16 + pt];
      #pragma unroll
      for (int f2 = 0; f2 < 4; ++f2) {
        acc[f2][fb] = __builtin_amdgcn_mfma_f32_16x16x32_bf16(ah[f2], bh, acc[f2][fb], 0, 0, 0);
        acc[f2][fb] = __builtin_amdgcn_mfma_f32_16x16x32_bf16(al[f2], bh, acc[f2][fb], 0, 0, 0);
        acc[f2][fb] = __builtin_amdgcn_mfma_f32_16x16x32_bf16(ah[f2], bl, acc[f2][fb], 0, 0, 0);
      }
    }
    __builtin_amdgcn_s_setprio(0);
  }

  #pragma unroll
  for (int f2 = 0; f2 < 4; ++f2) {
    #pragma unroll
    for (int r = 0; r < 4; ++r) {
      float bb = bvec[ow + f2 * 16 + kg * 4 + r];
      float mx = -1e30f, sm = 0.f;
      #pragma unroll
      for (int fb = 0; fb < 4; ++fb) {
        float y = leaky(acc[f2][fb][r] + bb);
        mx = fmaxf(mx, y);
        sm += y;
      }
      #pragma unroll
      for (int off = 1; off < 16; off <<= 1) {
        mx = fmaxf(mx, __shfl_xor(mx, off));
        sm += __shfl_xor(sm, off);
      }
      if (pt == 0) {
        redM[wv][f2 * 16 + kg * 4 + r] = mx;
        redS[wv][f2 * 16 + kg * 4 + r] = sm;
      }
    }
  }
  __syncthreads();
  if (tid < 128) {
    int os = tid >> 6, ol = tid & 63;
    float mx = fmaxf(redM[os * 2 + 0][ol], redM[os * 2 + 1][ol]);
    float sm = redS[os * 2 + 0][ol] + redS[os * 2 + 1][ol];
    float* pb = pbuf + (((long)(b * 8 + ob) * 16 + nt) * 2) * 128;
    pb[os * 64 + ol] = mx;
    pb[128 + os * 64 + ol] = sm;
  }
}

__global__ void mlp_reduce_kernel(const float* __restrict__ pbuf, float* __restrict__ feat) {
  int t = blockIdx.x * 256 + threadIdx.x;   // 8192
  int b = t >> 10, o = t & 1023;
  int ob = o >> 7, ol = o & 127;
  float mx = -1e30f, s = 0.f;
  for (int nt = 0; nt < 16; ++nt) {
    const float* pb = pbuf + (((long)(b * 8 + ob) * 16 + nt) * 2) * 128;
    mx = fmaxf(mx, pb[ol]);
    s += pb[128 + ol];
  }
  feat[b * 2048 + o] = mx;
  feat[b * 2048 + 1024 + o] = s * (1.f / 2048.f);
}

// ---------------- fc layers: one wave per output ----------------
__global__ void fc_kernel(const float* __restrict__ X, const float* __restrict__ W,
                          const float* __restrict__ bias, const float* __restrict__ g,
                          const float* __restrict__ bb, float* __restrict__ out,
                          int B, int O, int Kdim, int hasAct) {
  int gt = blockIdx.x * 256 + threadIdx.x;
  int wid = gt >> 6;
  int lane = threadIdx.x & 63;
  if (wid >= B * O) return;
  int b = wid / O, o = wid - b * O;
  const float* xr = X + (long)b * Kdim;
  const float* wr = W + (long)o * Kdim;
  float acc = 0.f;
  for (int c = lane; c < Kdim; c += 64) acc += xr[c] * wr[c];
  for (int off = 32; off; off >>= 1) acc += __shfl_down(acc, off);
  if (lane == 0) {
    float h = acc + bias[o];
    if (hasAct) {
      float a = g[o] * rsqrtf(1.0f + 1e-5f);
      h = a * h + bb[o];
      h = fmaxf(h, 0.2f * h);
    }
    out[b * O + o] = h;
  }
}

// ---------------- launch ----------------
extern "C" void kernel_launch(void* const* d_in, const int* in_sizes, int n_in,
                              void* d_out, int out_size, void* d_ws, size_t ws_size,
                              hipStream_t stream) {
  const float* points = (const float*)d_in[0];
  char* ws = (char*)d_ws;

  const size_t XCAT = 0;                         // [8][512][2048] f   (33.5 MB)
  const size_t VSUS = 33554432;                  // vsus fp32 (33.5 MB); aliases xqh/xql (mlp phase)
  const size_t XF   = 67108864;                  // xfh 4MB, xfl 4MB
  const size_t IDXB = 75497472;                  // pbuf (mlp partials)
  const size_t XXB  = 76808192;                  // [8][2048] f
  const size_t WPQ  = 76873728;                  // wpqh 128KB, wpql 128KB
  const size_t WMLP = 77135872;                  // wqh 1MB, wql 1MB
  const size_t FEAT = 79233024;                  // [8][2048] f
  const size_t H1   = 79298560;                  // [8][512] f
  const size_t H2   = 79314944;                  // [8][256] f
  const size_t KNND = 79331328;                  // packed partial lists, 5.24 MB (u32)

  float* xcat = (float*)(ws + XCAT);
  float* vsus = (float*)(ws + VSUS);
  float* xxb  = (float*)(ws + XXB);
  float* feat = (float*)(ws + FEAT);
  float* h1   = (float*)(ws + H1);
  float* h2   = (float*)(ws + H2);

  unsigned* knnD = (unsigned*)(ws + KNND);
  short* xfh = (short*)(ws + XF);
  short* xfl = (short*)(ws + XF + 4194304);
  short* xqh = (short*)(ws + VSUS);              // mlp phase (vsus dead)
  short* xql = (short*)(ws + VSUS + 16777216);
  float* pbuf = (float*)(ws + IDXB);
  short* wpqh = (short*)(ws + WPQ);
  short* wpql = (short*)(ws + WPQ + 131072);
  short* wqh = (short*)(ws + WMLP);
  short* wql = (short*)(ws + WMLP + 1048576);

  struct Layer { const float* x; long bstride; int C, O, cho, wi, gi, bi; };
  Layer layers[4] = {
    { points,              (long)3 * NPTS,   3,   64, 0,   1, 2, 3 },
    { xcat,                (long)512 * NPTS, 64,  64, 64,  4, 5, 6 },
    { xcat + 64 * NPTS,    (long)512 * NPTS, 64,  128, 128, 7, 8, 9 },
    { xcat + 128 * NPTS,   (long)512 * NPTS, 128, 256, 256, 10, 11, 12 },
  };

  for (int L = 0; L < 4; ++L) {
    Layer& ly = layers[L];
    int P2 = 2 * ly.O;
    const float* W = (const float*)d_in[ly.wi];
    const float* g = (const float*)d_in[ly.gi];
    const float* bv = (const float*)d_in[ly.bi];
    int NCHUNK = (ly.C + 31) / 32;

    prep_wpq_kernel<<<(NCHUNK * 4 * P2 + 255) / 256, 256, 0, stream>>>(
        W, g, wpqh, wpql, ly.O, ly.C, P2, NCHUNK);
    xx_kernel<<<dim3(NPTS / 256, BATCH), 256, 0, stream>>>(ly.x, xxb, ly.C, ly.bstride);
    split_kernel<<<dim3(NCHUNK * 32, BATCH), 256, 0, stream>>>(
        ly.x, xfh, xfl, ly.C, NCHUNK, ly.bstride);
    dim3 sg(NPTS / 64, KSPLIT, BATCH);
    dim3 vg(NPTS / 128, P2 / 128, BATCH);
    if (NCHUNK == 1) {
      knn_scan<1><<<sg, 256, 0, stream>>>(xfh, xfl, xxb, knnD);
      vsus_mfma_kernel<1><<<vg, 256, 0, stream>>>(xfh, xfl, wpqh, wpql, vsus, P2);
    } else if (NCHUNK == 2) {
      knn_scan<2><<<sg, 256, 0, stream>>>(xfh, xfl, xxb, knnD);
      vsus_mfma_kernel<2><<<vg, 256, 0, stream>>>(xfh, xfl, wpqh, wpql, vsus, P2);
    } else {
      knn_scan<4><<<sg, 256, 0, stream>>>(xfh, xfl, xxb, knnD);
      vsus_mfma_kernel<4><<<vg, 256, 0, stream>>>(xfh, xfl, wpqh, wpql, vsus, P2);
    }
    gather_max_kernel<<<(NPTS / 32) * BATCH, 256, 0, stream>>>(
        vsus, knnD, bv, xcat, ly.O, ly.cho);
  }

  prep_wq_kernel<<<256, 256, 0, stream>>>(
      (const float*)d_in[13], (const float*)d_in[14], wqh, wql);
  mlp_split_kernel<<<dim3(512, BATCH), 256, 0, stream>>>(xcat, xqh, xql);
  mlp_kernel<<<dim3(16, 8, BATCH), 256, 0, stream>>>(
      xqh, xql, wqh, wql, (const float*)d_in[15], pbuf);
  mlp_reduce_kernel<<<32, 256, 0, stream>>>(pbuf, feat);

  fc_kernel<<<(BATCH * 512 * 64) / 256, 256, 0, stream>>>(
      feat, (const float*)d_in[16], (const float*)d_in[17],
      (const float*)d_in[18], (const float*)d_in[19], h1, BATCH, 512, 2048, 1);
  fc_kernel<<<(BATCH * 256 * 64) / 256, 256, 0, stream>>>(
      h1, (const float*)d_in[20], (const float*)d_in[21],
      (const float*)d_in[22], (const float*)d_in[23], h2, BATCH, 256, 512, 1);
  fc_kernel<<<(BATCH * 40 * 64) / 256, 256, 0, stream>>>(
      h2, (const float*)d_in[24], (const float*)d_in[25],
      nullptr, nullptr, (float*)d_out, BATCH, 40, 256, 0);
}

// Round 22
// 430.873 us; speedup vs baseline: 1.0154x; 1.0154x over previous
//
#include <hip/hip_runtime.h>

#define NPTS 2048
#define BATCH 8
#define KNN 20
#define KSPLIT 4

typedef short short8v __attribute__((ext_vector_type(8)));
typedef float f32x4 __attribute__((ext_vector_type(4)));

__device__ __forceinline__ float leaky(float y) { return fmaxf(y, 0.2f * y); }

__device__ __forceinline__ short f2bf(float f) {
  unsigned u = __float_as_uint(f);
  unsigned r = (u + 0x7fffu + ((u >> 16) & 1u)) >> 16;
  return (short)r;
}
__device__ __forceinline__ float bf2f(short h) {
  return __uint_as_float(((unsigned)(unsigned short)h) << 16);
}

// med3(key, lo, hi) == min(max(key, lo), hi) when lo <= hi (sorted-list insert step).
__device__ __forceinline__ unsigned med3u(unsigned key, unsigned lo, unsigned hi) {
  unsigned t;
  asm("v_med3_u32 %0, %1, %2, %3" : "=v"(t) : "v"(key), "v"(lo), "v"(hi));
  return t;
}

// ---------------- prep edge-conv weight -> hi/lo bf16 quads, fragment layout ----------------
__global__ void prep_wpq_kernel(const float* __restrict__ W, const float* __restrict__ g,
                                short* __restrict__ wph, short* __restrict__ wpl,
                                int O, int C, int P2, int NCHUNK) {
  int t = blockIdx.x * 256 + threadIdx.x;
  if (t >= NCHUNK * 4 * P2) return;
  int cg = t / P2, p = t - cg * P2;
  int chunk = cg >> 2, gg = cg & 3;
  int po = (p < O) ? p : p - O;
  float s = g[po] * rsqrtf(1.0f + 1e-5f);
  short8v h8, l8;
  #pragma unroll
  for (int j = 0; j < 8; ++j) {
    int c = chunk * 32 + gg * 4 + (j & 3) + 16 * (j >> 2);
    float v = 0.f;
    if (c < C) {
      v = (p < O) ? s * W[p * 2 * C + c]
                  : s * (W[po * 2 * C + C + c] - W[po * 2 * C + c]);
    }
    short h = f2bf(v);
    h8[j] = h;
    l8[j] = f2bf(v - bf2f(h));
  }
  *reinterpret_cast<short8v*>(wph + (long)t * 8) = h8;
  *reinterpret_cast<short8v*>(wpl + (long)t * 8) = l8;
}

// prep mlp weight -> hi/lo bf16 quads, fragment layout, bn scale folded
__global__ void prep_wq_kernel(const float* __restrict__ W, const float* __restrict__ g,
                               short* __restrict__ wqh, short* __restrict__ wql) {
  int t = blockIdx.x * 256 + threadIdx.x;   // cg*1024 + o, cg < 64
  if (t >= 64 * 1024) return;
  int cg = t >> 10, o = t & 1023;
  int chunk = cg >> 2, gg = cg & 3;
  float scale = g[o] * rsqrtf(1.0f + 1e-5f);
  short8v h8, l8;
  #pragma unroll
  for (int j = 0; j < 8; ++j) {
    int c = chunk * 32 + gg * 4 + (j & 3) + 16 * (j >> 2);
    float v = scale * W[o * 512 + c];
    short h = f2bf(v);
    h8[j] = h;
    l8[j] = f2bf(v - bf2f(h));
  }
  *reinterpret_cast<short8v*>(wqh + (long)t * 8) = h8;
  *reinterpret_cast<short8v*>(wql + (long)t * 8) = l8;
}

// ---------------- xx[b][m] = sum_c x[c][m]^2 (exact fp32) ----------------
__global__ void xx_kernel(const float* __restrict__ x, float* __restrict__ xx,
                          int C, long bstride) {
  int b = blockIdx.y;
  int m = blockIdx.x * 256 + threadIdx.x;
  const float* xb = x + (long)b * bstride;
  float s = 0.f;
  for (int c = 0; c < C; ++c) { float v = xb[c * NPTS + m]; s += v * v; }
  xx[b * NPTS + m] = s;
}

// ---------------- split x into hi/lo bf16 fragment layout ----------------
__global__ void split_kernel(const float* __restrict__ x, short* __restrict__ xfh,
                             short* __restrict__ xfl, int C, int NCHUNK, long bstride) {
  int b = blockIdx.y;
  int t = blockIdx.x * 256 + threadIdx.x;   // cg*2048 + n
  int cg = t >> 11, n = t & 2047;
  int chunk = cg >> 2, g = cg & 3;
  const float* xb = x + (long)b * bstride;
  short8v h8, l8;
  #pragma unroll
  for (int j = 0; j < 8; ++j) {
    int c = chunk * 32 + g * 4 + (j & 3) + 16 * (j >> 2);
    float v = (c < C) ? xb[c * NPTS + n] : 0.f;
    short h = f2bf(v);
    float lo = v - bf2f(h);
    h8[j] = h;
    l8[j] = f2bf(lo);
  }
  long q = (long)b * NCHUNK * 4 * 2048 + t;
  *reinterpret_cast<short8v*>(xfh + q * 8) = h8;
  *reinterpret_cast<short8v*>(xfl + q * 8) = l8;
}

// ---------------- split xcat (all 512 ch) for mlp ----------------
__global__ void mlp_split_kernel(const float* __restrict__ xcat, short* __restrict__ xqh,
                                 short* __restrict__ xql) {
  int b = blockIdx.y;
  int t = blockIdx.x * 256 + threadIdx.x;   // cg*2048 + n, cg < 64
  int cg = t >> 11, n = t & 2047;
  int chunk = cg >> 2, g = cg & 3;
  const float* xb = xcat + (long)b * 512 * NPTS;
  short8v h8, l8;
  #pragma unroll
  for (int j = 0; j < 8; ++j) {
    int c = chunk * 32 + g * 4 + (j & 3) + 16 * (j >> 2);
    float v = xb[c * NPTS + n];
    short h = f2bf(v);
    h8[j] = h;
    l8[j] = f2bf(v - bf2f(h));
  }
  long q = (long)b * 64 * 2048 + t;
  *reinterpret_cast<short8v*>(xqh + q * 8) = h8;
  *reinterpret_cast<short8v*>(xql + q * 8) = l8;
}

// ---------------- knn scan: swapped-operand MFMA (3-product) + packed-u32 top-20 ----------------
template <int NCHUNK>
__global__ __launch_bounds__(256, 4) void knn_scan(const short* __restrict__ xfh,
                                                   const short* __restrict__ xfl,
                                                   const float* __restrict__ xx,
                                                   unsigned* __restrict__ pd) {
  __shared__ __align__(16) float smem[2080];   // qsm: 520 quads (8320 B)
  short8v* qsm = (short8v*)smem;
  unsigned* mD = (unsigned*)smem;              // alias (epilogue): [64][20] u32

  int tid = threadIdx.x;
  int lane = tid & 63, wv = tid >> 6;
  int pt = lane & 15;
  int kg = lane >> 4;
  int b = blockIdx.z;
  int sidx = blockIdx.y;
  int n0 = blockIdx.x * 64;
  const float* xxb = xx + b * NPTS;
  const short8v* xfh_b = (const short8v*)xfh + (long)b * NCHUNK * 4 * 2048;
  const short8v* xfl_b = (const short8v*)xfl + (long)b * NCHUNK * 4 * 2048;

  short8v bfh[NCHUNK], bfl[NCHUNK];
  #pragma unroll
  for (int c = 0; c < NCHUNK; ++c) {
    long qi = ((long)(c * 4 + kg)) * 2048 + n0 + wv * 16 + pt;
    bfh[c] = xfh_b[qi];
    bfl[c] = xfl_b[qi];
  }
  float xn = xxb[n0 + wv * 16 + pt];

  unsigned pl[20];
  #pragma unroll
  for (int k = 0; k < 20; ++k) pl[k] = 0xFFFFFFFFu;

  int mt0 = sidx * (32 / KSPLIT);

  short8v pA, pB;
  {
    long qi = ((long)(0 * 4 + wv)) * 2048 + mt0 * 64 + lane;
    pA = xfh_b[qi];
    pB = xfl_b[qi];
  }

  for (int mtl = 0; mtl < 32 / KSPLIT; ++mtl) {
    int m0 = (mt0 + mtl) * 64;
    float xpm[4][4];
    #pragma unroll
    for (int f = 0; f < 4; ++f) {
      f32x4 q = *reinterpret_cast<const f32x4*>(&xxb[m0 + f * 16 + kg * 4]);
      #pragma unroll
      for (int r = 0; r < 4; ++r) xpm[f][r] = (xn + 4.0f) + q[r];
    }
    f32x4 acc[4];
    #pragma unroll
    for (int f = 0; f < 4; ++f) acc[f] = (f32x4){0.f, 0.f, 0.f, 0.f};

    #pragma unroll
    for (int c = 0; c < NCHUNK; ++c) {
      __syncthreads();
      qsm[wv * 65 + lane] = pA;
      qsm[(4 + wv) * 65 + lane] = pB;
      __syncthreads();
      int nm = mtl, nc = c + 1;
      if (nc == NCHUNK) { nc = 0; nm = mtl + 1; }
      if (nm < 32 / KSPLIT) {
        long qi = ((long)(nc * 4 + wv)) * 2048 + (mt0 + nm) * 64 + lane;
        pA = xfh_b[qi];
        pB = xfl_b[qi];
      }
      // 3 products: hh, h*l, l*h (ll term ~2^-18 rel, far below key truncation)
      #pragma unroll
      for (int f = 0; f < 4; ++f) {
        short8v ah = qsm[kg * 65 + f * 16 + pt];
        short8v al = qsm[(4 + kg) * 65 + f * 16 + pt];
        acc[f] = __builtin_amdgcn_mfma_f32_16x16x32_bf16(ah, bfh[c], acc[f], 0, 0, 0);
        acc[f] = __builtin_amdgcn_mfma_f32_16x16x32_bf16(ah, bfl[c], acc[f], 0, 0, 0);
        acc[f] = __builtin_amdgcn_mfma_f32_16x16x32_bf16(al, bfh[c], acc[f], 0, 0, 0);
      }
    }

    #pragma unroll
    for (int f = 0; f < 4; ++f) {
      #pragma unroll
      for (int r = 0; r < 4; ++r) {
        float v = fmaf(-2.f, acc[f][r], xpm[f][r]);   // d2 + 4.0 (biased, positive)
        unsigned key = (__float_as_uint(v) & 0xFFFFF800u) | (unsigned)(m0 + f * 16 + kg * 4 + r);
        #pragma unroll
        for (int k = 19; k >= 1; --k)
          pl[k] = med3u(key, pl[k - 1], pl[k]);
        pl[0] = min(key, pl[0]);
      }
    }
  }
  __syncthreads();   // all MFMA/qsm use done; safe to alias mD

  // in-wave 4-way merge: point n's lists live at lanes {pt, pt+16, pt+32, pt+48}
  unsigned h = pl[0];
  #pragma unroll
  for (int k = 0; k < KNN; ++k) {
    unsigned v0 = (unsigned)__shfl((int)h, pt);
    unsigned v1 = (unsigned)__shfl((int)h, pt + 16);
    unsigned v2 = (unsigned)__shfl((int)h, pt + 32);
    unsigned v3 = (unsigned)__shfl((int)h, pt + 48);
    unsigned bv = v0; int bp = 0;
    if (v1 < bv) { bv = v1; bp = 1; }
    if (v2 < bv) { bv = v2; bp = 2; }
    if (v3 < bv) { bv = v3; bp = 3; }
    if (kg == 0) mD[(wv * 16 + pt) * KNN + k] = bv;
    bool pop = (kg == bp);
    #pragma unroll
    for (int i = 0; i < 19; ++i) pl[i] = pop ? pl[i + 1] : pl[i];
    pl[19] = pop ? 0xFFFFFFFFu : pl[19];
    h = pl[0];
  }
  __syncthreads();

  long base = ((long)((b * KSPLIT + sidx) * NPTS) + n0) * KNN;
  #pragma unroll
  for (int s = 0; s < 5; ++s) pd[base + s * 256 + tid] = mD[s * 256 + tid];
}

// ---------------- vsus via MFMA hi/lo (3 products): out[b][n][p] ----------------
template <int NCHUNK>
__global__ __launch_bounds__(256) void vsus_mfma_kernel(const short* __restrict__ xfh,
                                                        const short* __restrict__ xfl,
                                                        const short* __restrict__ wph,
                                                        const short* __restrict__ wpl,
                                                        float* __restrict__ out, int P2) {
  __shared__ __align__(16) short8v qsmX[2 * 4 * 130];   // [hl][g][130] quads
  int tid = threadIdx.x;
  int lane = tid & 63, wv = tid >> 6;
  int pt = lane & 15, kg = lane >> 4;
  int b = blockIdx.z, pb = blockIdx.y, nt = blockIdx.x;
  int n0 = nt * 128;
  int pw = pb * 128 + (wv >> 1) * 64;
  int nwoff = (wv & 1) * 64;
  const short8v* xh_b = (const short8v*)xfh + (long)b * NCHUNK * 4 * 2048;
  const short8v* xl_b = (const short8v*)xfl + (long)b * NCHUNK * 4 * 2048;
  const short8v* wh_q = (const short8v*)wph;
  const short8v* wl_q = (const short8v*)wpl;

  f32x4 acc[4][4];
  #pragma unroll
  for (int f2 = 0; f2 < 4; ++f2)
    #pragma unroll
    for (int fb = 0; fb < 4; ++fb) acc[f2][fb] = (f32x4){0.f, 0.f, 0.f, 0.f};

  for (int chunk = 0; chunk < NCHUNK; ++chunk) {
    __syncthreads();
    #pragma unroll
    for (int s = 0; s < 4; ++s) {
      int idx = s * 256 + tid;        // 0..1023
      int hl = idx >> 9, rem = idx & 511, g = rem >> 7, n = rem & 127;
      const short8v* src = hl ? xl_b : xh_b;
      qsmX[hl * 520 + g * 130 + n] = src[(long)(chunk * 4 + g) * 2048 + n0 + n];
    }
    __syncthreads();
    short8v ah[4], al[4];
    #pragma unroll
    for (int f2 = 0; f2 < 4; ++f2) {
      long qi = (long)(chunk * 4 + kg) * P2 + pw + f2 * 16 + pt;
      ah[f2] = wh_q[qi];
      al[f2] = wl_q[qi];
    }
    #pragma unroll
    for (int fb = 0; fb < 4; ++fb) {
      short8v bh = qsmX[0 * 520 + kg * 130 + nwoff + fb * 16 + pt];
      short8v bl = qsmX[1 * 520 + kg * 130 + nwoff + fb * 16 + pt];
      #pragma unroll
      for (int f2 = 0; f2 < 4; ++f2) {
        acc[f2][fb] = __builtin_amdgcn_mfma_f32_16x16x32_bf16(ah[f2], bh, acc[f2][fb], 0, 0, 0);
        acc[f2][fb] = __builtin_amdgcn_mfma_f32_16x16x32_bf16(al[f2], bh, acc[f2][fb], 0, 0, 0);
        acc[f2][fb] = __builtin_amdgcn_mfma_f32_16x16x32_bf16(ah[f2], bl, acc[f2][fb], 0, 0, 0);
      }
    }
  }

  #pragma unroll
  for (int f2 = 0; f2 < 4; ++f2) {
    #pragma unroll
    for (int fb = 0; fb < 4; ++fb) {
      int n = n0 + nwoff + fb * 16 + pt;
      *reinterpret_cast<f32x4*>(out + (long)(b * NPTS + n) * P2 + pw + f2 * 16 + kg * 4) =
          acc[f2][fb];
    }
  }
}

// ---------------- fused merge + gather + max_k + leaky -> xcat channel block ----------------
// 1D grid, b = blockIdx.x & 7 (XCD-affine): per-XCD vsus working set ~4.2 MB ~= L2.
__global__ __launch_bounds__(256) void gather_max_kernel(const float* __restrict__ vsus,
                                                         const unsigned* __restrict__ pd,
                                                         const float* __restrict__ bias,
                                                         float* __restrict__ xcat,
                                                         int O, int cho) {
  __shared__ __align__(16) float smemA[640 + 256 * 33];
  int* idxs = (int*)smemA;                       // [32][20]
  unsigned* plists = (unsigned*)(smemA + 640);   // phase 1: [4][32][20] u32 (10 KB)
  float* ot = smemA + 640;                       // phase 2: [256][33]

  int tid = threadIdx.x;
  int lin = blockIdx.x;
  int b = lin & 7;
  int n0 = (lin >> 3) * 32;
  int P2 = 2 * O;

  // phase 1: stage partial lists (each s-segment is contiguous in pd)
  for (int i = tid; i < KSPLIT * 32 * KNN; i += 256) {
    int s = i / (32 * KNN), rem = i - s * (32 * KNN);
    plists[i] = pd[((long)((b * KSPLIT + s) * NPTS) + n0) * KNN + rem];
  }
  __syncthreads();
  if (tid < 32) {
    int h0 = 0, h1 = 0, h2 = 0, h3 = 0;
    int base = tid * KNN;
    for (int k = 0; k < KNN; ++k) {
      unsigned v0 = plists[0 * 640 + base + h0];
      unsigned v1 = plists[1 * 640 + base + h1];
      unsigned v2 = plists[2 * 640 + base + h2];
      unsigned v3 = plists[3 * 640 + base + h3];
      unsigned bv = v0; int bp = 0;
      if (v1 < bv) { bv = v1; bp = 1; }
      if (v2 < bv) { bv = v2; bp = 2; }
      if (v3 < bv) { bv = v3; bp = 3; }
      idxs[base + k] = (int)(bv & 0x7FFu);
      h0 += (bp == 0); h1 += (bp == 1); h2 += (bp == 2); h3 += (bp == 3);
    }
  }
  __syncthreads();

  // phase 2: gather-max (plists dead; ot takes over the region)
  int G = 256 / O;
  int o = tid % O;
  int ns = tid / O;
  float bo = bias[o];
  const float* vb = vsus + (long)b * NPTS * P2;
  for (int step = 0; step < 32 / G; ++step) {
    int nn = step * G + ns;
    float mx = -1e30f;
    for (int k = 0; k < KNN; ++k) {
      int j = idxs[nn * KNN + k];
      mx = fmaxf(mx, vb[j * P2 + o]);
    }
    float us = vb[(n0 + nn) * P2 + O + o] + bo;
    ot[o * 33 + nn] = leaky(mx + us);
  }
  __syncthreads();
  float* ob = xcat + ((long)b * 512 + cho) * NPTS + n0;
  for (int i = tid; i < O * 32; i += 256) {
    int oo = i >> 5, nn = i & 31;
    ob[oo * NPTS + nn] = ot[oo * 33 + nn];
  }
}

// ---------------- mlp: MFMA hi/lo (3 products), 128x128 block, fused max/sum ----------------
__global__ __launch_bounds__(256) void mlp_kernel(const short* __restrict__ xqh,
                                                  const short* __restrict__ xql,
                                                  const short* __restrict__ wqh,
                                                  const short* __restrict__ wql,
                                                  const float* __restrict__ bvec,
                                                  float* __restrict__ pbuf) {
  __shared__ __align__(16) short8v qsmX[2 * 4 * 130];   // [hl][g][130] quads
  __shared__ float redM[4][64];
  __shared__ float redS[4][64];
  int tid = threadIdx.x;
  int lane = tid & 63, wv = tid >> 6;
  int pt = lane & 15, kg = lane >> 4;
  int b = blockIdx.z, ob = blockIdx.y, nt = blockIdx.x;
  int o0 = ob * 128, n0 = nt * 128;
  int ow = o0 + (wv >> 1) * 64;
  int nwoff = (wv & 1) * 64;
  const short8v* xqh_b = (const short8v*)xqh + (long)b * 64 * 2048;
  const short8v* xql_b = (const short8v*)xql + (long)b * 64 * 2048;
  const short8v* wqh_q = (const short8v*)wqh;
  const short8v* wql_q = (const short8v*)wql;

  f32x4 acc[4][4];
  #pragma unroll
  for (int f2 = 0; f2 < 4; ++f2)
    #pragma unroll
    for (int fb = 0; fb < 4; ++fb) acc[f2][fb] = (f32x4){0.f, 0.f, 0.f, 0.f};

  for (int chunk = 0; chunk < 16; ++chunk) {
    __syncthreads();
    #pragma unroll
    for (int s = 0; s < 4; ++s) {
      int idx = s * 256 + tid;        // 0..1023
      int hl = idx >> 9, rem = idx & 511, g = rem >> 7, n = rem & 127;
      const short8v* src = hl ? xql_b : xqh_b;
      qsmX[hl * 520 + g * 130 + n] = src[(long)(chunk * 4 + g) * 2048 + n0 + n];
    }
    __syncthreads();
    short8v ah[4], al[4];
    #pragma unroll
    for (int f2 = 0; f2 < 4; ++f2) {
      long qi = (long)(chunk * 4 + kg) * 1024 + ow + f2 * 16 + pt;
      ah[f2] = wqh_q[qi];
      al[f2] = wql_q[qi];
    }
    #pragma unroll
    for (int fb = 0; fb < 4; ++fb) {
      short8v bh = qsmX[0 * 520 + kg * 130 + nwoff + fb * 16 + pt];
      short8v bl = qsmX[1 * 520 + kg * 130 + nwoff + fb * 16 + pt];
      #pragma unroll
      for (int f2 = 0; f2 < 4; ++f2) {
        acc[f2][fb] = __builtin_amdgcn_mfma_f32_16x16x32_bf16(ah[f2], bh, acc[f2][fb], 0, 0, 0);
        acc[f2][fb] = __builtin_amdgcn_mfma_f32_16x16x32_bf16(al[f2], bh, acc[f2][fb], 0, 0, 0);
        acc[f2][fb] = __builtin_amdgcn_mfma_f32_16x16x32_bf16(ah[f2], bl, acc[f2][fb], 0, 0, 0);
      }
    }
  }

  #pragma unroll
  for (int f2 = 0; f2 < 4; ++f2) {
    #pragma unroll
    for (int r = 0; r < 4; ++r) {
      float bb = bvec[ow + f2 * 16 + kg * 4 + r];
      float mx = -1e30f, sm = 0.f;
      #pragma unroll
      for (int fb = 0; fb < 4; ++fb) {
        float y = leaky(acc[f2][fb][r] + bb);
        mx = fmaxf(mx, y);
        sm += y;
      }
      #pragma unroll
      for (int off = 1; off < 16; off <<= 1) {
        mx = fmaxf(mx, __shfl_xor(mx, off));
        sm += __shfl_xor(sm, off);
      }
      if (pt == 0) {
        redM[wv][f2 * 16 + kg * 4 + r] = mx;
        redS[wv][f2 * 16 + kg * 4 + r] = sm;
      }
    }
  }
  __syncthreads();
  if (tid < 128) {
    int os = tid >> 6, ol = tid & 63;
    float mx = fmaxf(redM[os * 2 + 0][ol], redM[os * 2 + 1][ol]);
    float sm = redS[os * 2 + 0][ol] + redS[os * 2 + 1][ol];
    float* pb = pbuf + (((long)(b * 8 + ob) * 16 + nt) * 2) * 128;
    pb[os * 64 + ol] = mx;
    pb[128 + os * 64 + ol] = sm;
  }
}

__global__ void mlp_reduce_kernel(const float* __restrict__ pbuf, float* __restrict__ feat) {
  int t = blockIdx.x * 256 + threadIdx.x;   // 8192
  int b = t >> 10, o = t & 1023;
  int ob = o >> 7, ol = o & 127;
  float mx = -1e30f, s = 0.f;
  for (int nt = 0; nt < 16; ++nt) {
    const float* pb = pbuf + (((long)(b * 8 + ob) * 16 + nt) * 2) * 128;
    mx = fmaxf(mx, pb[ol]);
    s += pb[128 + ol];
  }
  feat[b * 2048 + o] = mx;
  feat[b * 2048 + 1024 + o] = s * (1.f / 2048.f);
}

// ---------------- fc layers: one wave per output ----------------
__global__ void fc_kernel(const float* __restrict__ X, const float* __restrict__ W,
                          const float* __restrict__ bias, const float* __restrict__ g,
                          const float* __restrict__ bb, float* __restrict__ out,
                          int B, int O, int Kdim, int hasAct) {
  int gt = blockIdx.x * 256 + threadIdx.x;
  int wid = gt >> 6;
  int lane = threadIdx.x & 63;
  if (wid >= B * O) return;
  int b = wid / O, o = wid - b * O;
  const float* xr = X + (long)b * Kdim;
  const float* wr = W + (long)o * Kdim;
  float acc = 0.f;
  for (int c = lane; c < Kdim; c += 64) acc += xr[c] * wr[c];
  for (int off = 32; off; off >>= 1) acc += __shfl_down(acc, off);
  if (lane == 0) {
    float h = acc + bias[o];
    if (hasAct) {
      float a = g[o] * rsqrtf(1.0f + 1e-5f);
      h = a * h + bb[o];
      h = fmaxf(h, 0.2f * h);
    }
    out[b * O + o] = h;
  }
}

// ---------------- launch ----------------
extern "C" void kernel_launch(void* const* d_in, const int* in_sizes, int n_in,
                              void* d_out, int out_size, void* d_ws, size_t ws_size,
                              hipStream_t stream) {
  const float* points = (const float*)d_in[0];
  char* ws = (char*)d_ws;

  const size_t XCAT = 0;                         // [8][512][2048] f   (33.5 MB)
  const size_t VSUS = 33554432;                  // vsus fp32 (33.5 MB); aliases xqh/xql (mlp phase)
  const size_t XF   = 67108864;                  // xfh 4MB, xfl 4MB
  const size_t IDXB = 75497472;                  // pbuf (mlp partials)
  const size_t XXB  = 76808192;                  // [8][2048] f
  const size_t WPQ  = 76873728;                  // wpqh 128KB, wpql 128KB
  const size_t WMLP = 77135872;                  // wqh 1MB, wql 1MB
  const size_t FEAT = 79233024;                  // [8][2048] f
  const size_t H1   = 79298560;                  // [8][512] f
  const size_t H2   = 79314944;                  // [8][256] f
  const size_t KNND = 79331328;                  // packed partial lists, 5.24 MB (u32)

  float* xcat = (float*)(ws + XCAT);
  float* vsus = (float*)(ws + VSUS);
  float* xxb  = (float*)(ws + XXB);
  float* feat = (float*)(ws + FEAT);
  float* h1   = (float*)(ws + H1);
  float* h2   = (float*)(ws + H2);

  unsigned* knnD = (unsigned*)(ws + KNND);
  short* xfh = (short*)(ws + XF);
  short* xfl = (short*)(ws + XF + 4194304);
  short* xqh = (short*)(ws + VSUS);              // mlp phase (vsus dead)
  short* xql = (short*)(ws + VSUS + 16777216);
  float* pbuf = (float*)(ws + IDXB);
  short* wpqh = (short*)(ws + WPQ);
  short* wpql = (short*)(ws + WPQ + 131072);
  short* wqh = (short*)(ws + WMLP);
  short* wql = (short*)(ws + WMLP + 1048576);

  struct Layer { const float* x; long bstride; int C, O, cho, wi, gi, bi; };
  Layer layers[4] = {
    { points,              (long)3 * NPTS,   3,   64, 0,   1, 2, 3 },
    { xcat,                (long)512 * NPTS, 64,  64, 64,  4, 5, 6 },
    { xcat + 64 * NPTS,    (long)512 * NPTS, 64,  128, 128, 7, 8, 9 },
    { xcat + 128 * NPTS,   (long)512 * NPTS, 128, 256, 256, 10, 11, 12 },
  };

  for (int L = 0; L < 4; ++L) {
    Layer& ly = layers[L];
    int P2 = 2 * ly.O;
    const float* W = (const float*)d_in[ly.wi];
    const float* g = (const float*)d_in[ly.gi];
    const float* bv = (const float*)d_in[ly.bi];
    int NCHUNK = (ly.C + 31) / 32;

    prep_wpq_kernel<<<(NCHUNK * 4 * P2 + 255) / 256, 256, 0, stream>>>(
        W, g, wpqh, wpql, ly.O, ly.C, P2, NCHUNK);
    xx_kernel<<<dim3(NPTS / 256, BATCH), 256, 0, stream>>>(ly.x, xxb, ly.C, ly.bstride);
    split_kernel<<<dim3(NCHUNK * 32, BATCH), 256, 0, stream>>>(
        ly.x, xfh, xfl, ly.C, NCHUNK, ly.bstride);
    dim3 sg(NPTS / 64, KSPLIT, BATCH);
    dim3 vg(NPTS / 128, P2 / 128, BATCH);
    if (NCHUNK == 1) {
      knn_scan<1><<<sg, 256, 0, stream>>>(xfh, xfl, xxb, knnD);
      vsus_mfma_kernel<1><<<vg, 256, 0, stream>>>(xfh, xfl, wpqh, wpql, vsus, P2);
    } else if (NCHUNK == 2) {
      knn_scan<2><<<sg, 256, 0, stream>>>(xfh, xfl, xxb, knnD);
      vsus_mfma_kernel<2><<<vg, 256, 0, stream>>>(xfh, xfl, wpqh, wpql, vsus, P2);
    } else {
      knn_scan<4><<<sg, 256, 0, stream>>>(xfh, xfl, xxb, knnD);
      vsus_mfma_kernel<4><<<vg, 256, 0, stream>>>(xfh, xfl, wpqh, wpql, vsus, P2);
    }
    gather_max_kernel<<<(NPTS / 32) * BATCH, 256, 0, stream>>>(
        vsus, knnD, bv, xcat, ly.O, ly.cho);
  }

  prep_wq_kernel<<<256, 256, 0, stream>>>(
      (const float*)d_in[13], (const float*)d_in[14], wqh, wql);
  mlp_split_kernel<<<dim3(512, BATCH), 256, 0, stream>>>(xcat, xqh, xql);
  mlp_kernel<<<dim3(16, 8, BATCH), 256, 0, stream>>>(
      xqh, xql, wqh, wql, (const float*)d_in[15], pbuf);
  mlp_reduce_kernel<<<32, 256, 0, stream>>>(pbuf, feat);

  fc_kernel<<<(BATCH * 512 * 64) / 256, 256, 0, stream>>>(
      feat, (const float*)d_in[16], (const float*)d_in[17],
      (const float*)d_in[18], (const float*)d_in[19], h1, BATCH, 512, 2048, 1);
  fc_kernel<<<(BATCH * 256 * 64) / 256, 256, 0, stream>>>(
      h1, (const float*)d_in[20], (const float*)d_in[21],
      (const float*)d_in[22], (const float*)d_in[23], h2, BATCH, 256, 512, 1);
  fc_kernel<<<(BATCH * 40 * 64) / 256, 256, 0, stream>>>(
      h2, (const float*)d_in[24], (const float*)d_in[25],
      nullptr, nullptr, (float*)d_out, BATCH, 40, 256, 0);
}